// Round 18
// baseline (110.664 us; speedup 1.0000x reference)
//
#include <hip/hip_runtime.h>
#include <hip/hip_bf16.h>

// B=2, S=2048, D=1024, H=16, HD=64. Causal MHA + RoPE.
// prep (cast+trans+rope) -> fused QKV GEMM (256x64 tile, 768 blocks = 3/CU;
//   bf16 A via async DMA; BK=64, swizzled; RoPE fused) ->
//   MFMA flash attn v10 (R15 config) -> out GEMM (64x64 tile, 4/CU).
// ws: Xc 8MB | Wt 8MB | QKV 24MB | Ac 8MB | rope_tab 0.5MB

#define S_ 2048
#define DM 1024
#define HD 64

typedef __attribute__((ext_vector_type(8))) short short8;   // 8 bf16
typedef __attribute__((ext_vector_type(4))) float floatx4;  // 4 f32

__device__ __forceinline__ unsigned short f2b(float x) {
  union { __hip_bfloat16 h; unsigned short u; } cv;
  cv.h = __float2bfloat16(x);
  return cv.u;
}

// pack two f32 -> dword of 2 bf16 (lo in [15:0], hi in [31:16]) in ONE VALU op
__device__ __forceinline__ unsigned cvt_pk_bf16(float lo, float hi) {
  unsigned r;
  asm("v_cvt_pk_bf16_f32 %0, %1, %2" : "=v"(r) : "v"(lo), "v"(hi));
  return r;
}

__device__ __forceinline__ void gload_lds16(const unsigned short* g, unsigned short* l) {
  typedef const __attribute__((address_space(1))) unsigned int* gp_t;
  typedef __attribute__((address_space(3))) unsigned int* lp_t;
  __builtin_amdgcn_global_load_lds((gp_t)(const void*)g, (lp_t)(void*)l, 16, 0, 0);
}

// ---------------- prep: cast x -> bf16 | transpose weights | rope table ----------------
// grid 8448 x 256: [0,4096) cast, [4096,8192) trans, [8192,8448) rope.
__global__ void prep_kernel(const float* __restrict__ x,
                            const float* __restrict__ w0, const float* __restrict__ w1,
                            const float* __restrict__ w2, const float* __restrict__ w3,
                            unsigned short* __restrict__ xc,
                            unsigned short* __restrict__ wt,
                            float2* __restrict__ rope) {
  const int bid = blockIdx.x;
  if (bid < 4096) {                       // cast: 4 f32 -> bf16 per thread
    int i = (bid * 256 + threadIdx.x) * 4;
    float4 v = *(const float4*)(x + i);
    ushort4 o;
    o.x = f2b(v.x); o.y = f2b(v.y); o.z = f2b(v.z); o.w = f2b(v.w);
    *(ushort4*)(xc + i) = o;
  } else if (bid < 8192) {                // weight transpose: Wt[n][k] = W[k][n]
    __shared__ float tile[32][33];
    const int rem = bid - 4096;
    const int z = rem >> 10;
    const int bx = (rem & 1023) & 31;
    const int by = (rem & 1023) >> 5;
    const float* W = (z == 0) ? w0 : (z == 1) ? w1 : (z == 2) ? w2 : w3;
    unsigned short* Wt = wt + (size_t)z * DM * DM;
    const int tx = threadIdx.x & 31;
    const int ty = threadIdx.x >> 5;
    const int k0 = bx * 32;
    const int c0 = by * 32;
#pragma unroll
    for (int i = 0; i < 4; ++i)
      tile[ty + i * 8][tx] = W[(size_t)(k0 + ty + i * 8) * DM + c0 + tx];
    __syncthreads();
#pragma unroll
    for (int i = 0; i < 4; ++i)
      Wt[(size_t)(c0 + ty + i * 8) * DM + k0 + tx] = f2b(tile[tx][ty + i * 8]);
  } else {                                // rope: tab[s][d2] = (cos, sin)
    int i = (bid - 8192) * 256 + threadIdx.x;  // 65536 = 2048*32
    int s = i >> 5, d2 = i & 31;
    float th = expf(-(float)d2 * (9.210340371976184f / 32.0f));
    float sn, cs;
    sincosf((float)s * th, &sn, &cs);
    rope[i] = make_float2(cs, sn);
  }
}

// ---------------- fused QKV GEMM: 256x64 tile, 768 blocks = 3/CU ----------------
// A[4096][1024] bf16 x Wt_qkv[3072][1024]^T. grid (16,48). mat = by>>4.
// 0=Q (RoPE + 0.125*log2e), 1=K (RoPE), 2=V. bf16 out [mat][bh][s][d].
__global__ __launch_bounds__(256, 3) void gemm_qkv(
    const unsigned short* __restrict__ A, const unsigned short* __restrict__ Wt,
    const float* __restrict__ bq, const float* __restrict__ bk,
    const float* __restrict__ bv, const float2* __restrict__ rope,
    unsigned short* __restrict__ QKV) {
  __shared__ __attribute__((aligned(16))) unsigned short As[256 * 64];
  __shared__ __attribute__((aligned(16))) unsigned short Bs[64 * 64];
  const int r0 = blockIdx.x * 256;
  const int c0 = blockIdx.y * 64;
  const int t = threadIdx.x;
  const int lane = t & 63;
  const int wv = t >> 6;
  const int wr = (wv >> 1) * 128;  // 2 wave-rows x 128
  const int wc = (wv & 1) * 32;    // 2 wave-cols x 32
  const int lr = lane & 15;
  const int lg = lane >> 4;

  // staging: A rows [wv*64,+64) via 8 gloads; B rows [wv*16,+16) via 2 gloads
  const int chunk = lane >> 3;
  const int sseg = ((lane & 7) ^ chunk) * 8;
  const unsigned short* Ag = A + (size_t)(r0 + wv * 64 + chunk) * DM + sseg;
  const unsigned short* Bg = Wt + (size_t)(c0 + wv * 16 + chunk) * DM + sseg;
  unsigned short* lA = &As[wv * 64 * 64];
  unsigned short* lB = &Bs[wv * 16 * 64];

  floatx4 acc[8][2] = {};
  const int fswz = (lr & 7) << 4;

  for (int k0 = 0; k0 < DM; k0 += 64) {
#pragma unroll
    for (int j = 0; j < 8; ++j)
      gload_lds16(Ag + k0 + j * 8 * DM, lA + j * 8 * 64);
#pragma unroll
    for (int j = 0; j < 2; ++j)
      gload_lds16(Bg + k0 + j * 8 * DM, lB + j * 8 * 64);
    __syncthreads();
#pragma unroll
    for (int kk = 0; kk < 2; ++kk) {
      short8 bf[2];
#pragma unroll
      for (int n = 0; n < 2; ++n)
        bf[n] = *(const short8*)((char*)Bs + (wc + n * 16 + lr) * 128 +
                                 ((kk * 64 + lg * 16) ^ fswz));
#pragma unroll
      for (int m = 0; m < 8; ++m) {
        short8 af = *(const short8*)((char*)As + (wr + m * 16 + lr) * 128 +
                                     ((kk * 64 + lg * 16) ^ fswz));
#pragma unroll
        for (int n = 0; n < 2; ++n)
          acc[m][n] = __builtin_amdgcn_mfma_f32_16x16x32_bf16(af, bf[n], acc[m][n], 0, 0, 0);
      }
    }
    __syncthreads();
  }

  const int mat = blockIdx.y >> 4;
  const float* bias = (mat == 0) ? bq : (mat == 1) ? bk : bv;
  const int rbase = r0 + wr + lg * 4;
  const int cbase = c0 + wc + lr;
#pragma unroll
  for (int n = 0; n < 2; ++n) {
    const int c = cbase + n * 16;
    const int cc = c & (DM - 1);
    const float bvv = bias[cc];
    const int d = c & 63;
    const int h = cc >> 6;
#pragma unroll
    for (int m = 0; m < 8; ++m) {
#pragma unroll
      for (int i = 0; i < 4; ++i) {
        const int r = rbase + m * 16 + i;
        const int s = r & (S_ - 1);
        const int b = r >> 11;
        float v = acc[m][n][i] + bvv;
        float pv = __shfl_xor(v, 1);
        if (mat < 2) {
          float2 cssn = rope[s * 32 + (d >> 1)];
          v = (d & 1) ? fmaf(v, cssn.x, pv * cssn.y) : fmaf(v, cssn.x, -pv * cssn.y);
          if (mat == 0) v *= 0.18033688011112042f;  // 0.125 * log2(e)
        }
        QKV[((size_t)((mat << 5) | (b << 4) | h) * S_ + s) * HD + d] = f2b(v);
      }
    }
  }
}

// ---------------- out projection GEMM: 64x64 tile, 1024 blocks = 4/CU ----------------
__global__ __launch_bounds__(256, 4) void gemm_out(
    const unsigned short* __restrict__ A, const unsigned short* __restrict__ Wt,
    const float* __restrict__ bias, float* __restrict__ out) {
  __shared__ __attribute__((aligned(16))) unsigned short As[64 * 64];
  __shared__ __attribute__((aligned(16))) unsigned short Bs[64 * 64];
  const int r0 = blockIdx.x * 64;
  const int c0 = blockIdx.y * 64;
  const int t = threadIdx.x;
  const int lane = t & 63;
  const int wv = t >> 6;
  const int wr = (wv >> 1) * 32;
  const int wc = (wv & 1) * 32;
  const int lr = lane & 15;
  const int lg = lane >> 4;

  const int chunk = lane >> 3;
  const int sseg = ((lane & 7) ^ chunk) * 8;
  const unsigned short* Ag = A + (size_t)(r0 + wv * 8 + chunk) * DM + sseg;
  const unsigned short* Bg = Wt + (size_t)(c0 + wv * 8 + chunk) * DM + sseg;
  unsigned short* lA = &As[wv * 8 * 64];
  unsigned short* lB = &Bs[wv * 8 * 64];

  floatx4 acc[2][2] = {};
  const int fswz = (lr & 7) << 4;

  for (int k0 = 0; k0 < DM; k0 += 64) {
#pragma unroll
    for (int j = 0; j < 2; ++j) {
      gload_lds16(Ag + k0 + j * 32 * DM, lA + j * 32 * 64);
      gload_lds16(Bg + k0 + j * 32 * DM, lB + j * 32 * 64);
    }
    __syncthreads();
#pragma unroll
    for (int kk = 0; kk < 2; ++kk) {
      short8 af[2], bf[2];
#pragma unroll
      for (int m = 0; m < 2; ++m)
        af[m] = *(const short8*)((char*)As + (wr + m * 16 + lr) * 128 +
                                 ((kk * 64 + lg * 16) ^ fswz));
#pragma unroll
      for (int n = 0; n < 2; ++n)
        bf[n] = *(const short8*)((char*)Bs + (wc + n * 16 + lr) * 128 +
                                 ((kk * 64 + lg * 16) ^ fswz));
#pragma unroll
      for (int m = 0; m < 2; ++m)
#pragma unroll
        for (int n = 0; n < 2; ++n)
          acc[m][n] = __builtin_amdgcn_mfma_f32_16x16x32_bf16(af[m], bf[n], acc[m][n], 0, 0, 0);
    }
    __syncthreads();
  }

  const int rbase = r0 + wr + lg * 4;
  const int cbase = c0 + wc + lr;
#pragma unroll
  for (int n = 0; n < 2; ++n) {
    const int c = cbase + n * 16;
    const float bvv = bias[c];
#pragma unroll
    for (int m = 0; m < 2; ++m) {
#pragma unroll
      for (int i = 0; i < 4; ++i) {
        const int r = rbase + m * 16 + i;
        out[(size_t)r * DM + c] = acc[m][n][i] + bvv;
      }
    }
  }
}

// ---------------- MFMA flash attention v10 (R15 config): lazy cross-lane max ----------------
#define ATTN_STEP(TT, BUF, KLA, KLB)                                           \
  do {                                                                         \
    { /* (a) V regs (tile TT) -> Vs[BUF], transposed+paired */                 \
      char* Vb = (char*)Vs[BUF];                                               \
      const unsigned* ua = (const unsigned*)&va;                               \
      const unsigned* ub = (const unsigned*)&vb;                               \
      _Pragma("unroll") for (int j = 0; j < 8; ++j) {                          \
        unsigned pkv = __builtin_amdgcn_perm(                                  \
            ub[j >> 1], ua[j >> 1], (j & 1) ? 0x07060302u : 0x05040100u);      \
        *(unsigned*)(Vb + (oct * 8 + j) * 128 + ((4 * kp) ^ (j << 4))) = pkv;  \
      }                                                                        \
    }                                                                          \
    if ((TT) < qt) { /* (b) V prefetch (TT+1) */                               \
      va = *(const short8*)(Vpref);                                            \
      vb = *(const short8*)(Vpref + 64);                                       \
      Vpref += 4096;                                                           \
    }                                                                          \
    /* (c) barrier: LDS drain only, VMEM stays in flight */                    \
    asm volatile("s_waitcnt lgkmcnt(0)" ::: "memory");                         \
    __builtin_amdgcn_s_barrier();                                              \
    /* (d) wait K-DMA(TT); 2 newer V loads may remain in flight */             \
    if ((TT) < qt) asm volatile("s_waitcnt vmcnt(2)" ::: "memory");            \
    else           asm volatile("s_waitcnt vmcnt(0)" ::: "memory");            \
    __builtin_amdgcn_sched_barrier(0);                                         \
    if ((TT) < qt) { /* (e) K DMA for TT+1 -> other buffer */                  \
      gload_lds16(Kpref, KLA);                                                 \
      gload_lds16(Kpref + 2048, KLB);                                          \
      Kpref += 4096;                                                           \
    }                                                                          \
    /* (f) S^T = K Q^T : s[n][i] = S[key=n*16+lg*4+i][q=lr] */                 \
    floatx4 s[4] = {};                                                         \
    __builtin_amdgcn_s_setprio(1);                                             \
    _Pragma("unroll") for (int kk = 0; kk < 2; ++kk) {                         \
      _Pragma("unroll") for (int n = 0; n < 4; ++n) {                          \
        int r = n * 16 + lr;                                                   \
        short8 kf = *(const short8*)((char*)Ks[BUF] + r * 128 +                \
                                     ((kk * 64 + lg * 16) ^ ((r & 7) << 4)));  \
        s[n] = __builtin_amdgcn_mfma_f32_16x16x32_bf16(kf, qf[kk], s[n], 0, 0, 0); \
      }                                                                        \
    }                                                                          \
    __builtin_amdgcn_s_setprio(0);                                             \
    if ((TT) == qt) {                                                          \
      _Pragma("unroll") for (int n = 0; n < 4; ++n)                            \
        _Pragma("unroll") for (int i = 0; i < 4; ++i)                          \
          if (n * 16 + lg * 4 + i > qin) s[n][i] = -1e30f;                     \
    }                                                                          \
    /* in-lane 16-max only (max3-friendly triples) */                          \
    float ta = fmaxf(fmaxf(s[0][0], s[0][1]), s[0][2]);                        \
    float tb = fmaxf(fmaxf(s[0][3], s[1][0]), s[1][1]);                        \
    float tc = fmaxf(fmaxf(s[1][2], s[1][3]), s[2][0]);                        \
    float td = fmaxf(fmaxf(s[2][1], s[2][2]), s[2][3]);                        \
    float te = fmaxf(fmaxf(s[3][0], s[3][1]), s[3][2]);                        \
    float tm = fmaxf(fmaxf(ta, tb), tc);                                       \
    tm = fmaxf(fmaxf(tm, td), te);                                             \
    tm = fmaxf(tm, s[3][3]);                                                   \
    /* lazy max: cross-lane shuffles + rescale only when triggered */          \
    if (__any(tm > m + 8.f)) {                                                 \
      tm = fmaxf(tm, __shfl_xor(tm, 16));                                      \
      tm = fmaxf(tm, __shfl_xor(tm, 32));                                      \
      const float mn = fmaxf(m, tm);                                           \
      const float al = exp2f(m - mn);                                          \
      m = mn;                                                                  \
      lsum *= al;                                                              \
      _Pragma("unroll") for (int dd = 0; dd < 4; ++dd) o[dd] *= al;            \
    }                                                                          \
    float ps = 0.f;                                                            \
    _Pragma("unroll") for (int n = 0; n < 4; ++n) {                            \
      _Pragma("unroll") for (int i = 0; i < 4; ++i) {                          \
        float p = exp2f(s[n][i] - m);                                          \
        s[n][i] = p;                                                           \
        ps += p;                                                               \
      }                                                                        \
    }                                                                          \
    lsum += ps;                                                                \
    /* P^T rows into Ps[w] via cvt_pk (1 VALU per pair) */                     \
    _Pragma("unroll") for (int n = 0; n < 4; ++n) {                            \
      _Pragma("unroll") for (int hh = 0; hh < 2; ++hh) {                       \
        unsigned pk = cvt_pk_bf16(s[n][2 * hh], s[n][2 * hh + 1]);             \
        *(unsigned*)(Pw + lr * 128 +                                           \
                     (((n * 16 + lg * 4 + 2 * hh) * 2) ^ pswz)) = pk;          \
      }                                                                        \
    }                                                                          \
    short8 pb[2];                                                              \
    _Pragma("unroll") for (int kk = 0; kk < 2; ++kk)                           \
      pb[kk] = *(const short8*)(Pw + lr * 128 + ((kk * 64 + lg * 16) ^ pswz)); \
    __builtin_amdgcn_s_setprio(1);                                             \
    _Pragma("unroll") for (int kk = 0; kk < 2; ++kk)                           \
      _Pragma("unroll") for (int dd = 0; dd < 4; ++dd) {                       \
        int d = dd * 16 + lr;                                                  \
        short8 vbf = *(const short8*)((char*)Vs[BUF] + d * 128 +               \
                                      ((kk * 64 + lg * 16) ^ ((d & 7) << 4))); \
        o[dd] = __builtin_amdgcn_mfma_f32_16x16x32_bf16(vbf, pb[kk], o[dd], 0, 0, 0); \
      }                                                                        \
    __builtin_amdgcn_s_setprio(0);                                             \
  } while (0)

__global__ __launch_bounds__(256, 4) void attn_kernel(
    const unsigned short* __restrict__ Q, const unsigned short* __restrict__ K,
    const unsigned short* __restrict__ V, unsigned short* __restrict__ AttnC) {
  __shared__ __attribute__((aligned(16))) unsigned short Ks[2][64 * 64];
  __shared__ __attribute__((aligned(16))) unsigned short Vs[2][64 * 64];
  __shared__ __attribute__((aligned(16))) unsigned short Ps[4][16 * 64];

  const int bh = blockIdx.x;
  const int qt = 31 - (int)blockIdx.y;  // LPT: big blocks first
  const int tid = threadIdx.x;
  const int w = tid >> 6;
  const int l = tid & 63;
  const int lg = l >> 4;
  const int lr = l & 15;
  const size_t base = (size_t)bh * S_ * HD;
  const int qin = w * 16 + lr;

  // Q as B-frag: B[k][q=lr] = Q[q][k], k = kk*32 + lg*8 + j
  short8 qf[2];
  {
    const unsigned short* Qrow =
        Q + base + (size_t)(qt * 64 + w * 16 + lr) * HD + lg * 8;
    qf[0] = *(const short8*)(Qrow);
    qf[1] = *(const short8*)(Qrow + 32);
  }

  floatx4 o[4] = {};
  float m = -1e30f, lsum = 0.f;

  // K staging: pre-swizzled global source -> linear LDS via global_load_lds.
  const int krow = tid >> 3;
  const int kseg = tid & 7;
  const unsigned short* Kpref = K + base + krow * 64 + ((kseg ^ (krow & 7)) * 8);
  unsigned short* const kld0a = &Ks[0][w * 512];
  unsigned short* const kld0b = &Ks[0][2048 + w * 512];
  unsigned short* const kld1a = &Ks[1][w * 512];
  unsigned short* const kld1b = &Ks[1][2048 + w * 512];

  // V staging roles: key-pair 2kp,2kp+1, dims oct*8..+8
  const int oct = tid >> 5;
  const int kp = tid & 31;
  const unsigned short* Vpref = V + base + 2 * kp * 64 + oct * 8;

  // prologue: V regs first, then K DMA (so V-use waits vmcnt(2), not 0)
  short8 va = *(const short8*)(Vpref);
  short8 vb = *(const short8*)(Vpref + 64);
  Vpref += 4096;
  gload_lds16(Kpref, kld0a);
  gload_lds16(Kpref + 2048, kld0b);
  Kpref += 4096;

  char* const Pw = (char*)Ps[w];
  const int pswz = (lr & 7) << 4;

  int t = 0;
#pragma unroll 1
  for (; t + 1 <= qt; t += 2) {
    ATTN_STEP(t, 0, kld1a, kld1b);
    ATTN_STEP(t + 1, 1, kld0a, kld0b);
  }
  if (t <= qt) ATTN_STEP(t, 0, kld1a, kld1b);

  // reduce lsum across the 4 lg-partials, write O[q=lr][d=dd*16+lg*4+i]
  lsum += __shfl_xor(lsum, 16);
  lsum += __shfl_xor(lsum, 32);
  const float inv = 1.f / lsum;
  unsigned short* orow =
      AttnC + (size_t)((bh >> 4) * S_ + qt * 64 + w * 16 + lr) * DM + (bh & 15) * HD;
#pragma unroll
  for (int dd = 0; dd < 4; ++dd) {
    unsigned w0 = cvt_pk_bf16(o[dd][0] * inv, o[dd][1] * inv);
    unsigned w1 = cvt_pk_bf16(o[dd][2] * inv, o[dd][3] * inv);
    *(uint2*)(orow + dd * 16 + lg * 4) = make_uint2(w0, w1);
  }
}

extern "C" void kernel_launch(void* const* d_in, const int* in_sizes, int n_in,
                              void* d_out, int out_size, void* d_ws, size_t ws_size,
                              hipStream_t stream) {
  const float* x = (const float*)d_in[0];
  const float* wq = (const float*)d_in[2];
  const float* bq = (const float*)d_in[3];
  const float* wk = (const float*)d_in[4];
  const float* bk = (const float*)d_in[5];
  const float* wv = (const float*)d_in[6];
  const float* bv = (const float*)d_in[7];
  const float* wo = (const float*)d_in[8];
  const float* bo = (const float*)d_in[9];

  char* ws = (char*)d_ws;
  const size_t MB = 1024ull * 1024ull;
  unsigned short* Xc = (unsigned short*)(ws);             // 8 MB
  unsigned short* Wt = (unsigned short*)(ws + 8 * MB);    // 4 x 2 MB
  unsigned short* QKVb = (unsigned short*)(ws + 16 * MB); // 24 MB
  unsigned short* Ac = (unsigned short*)(ws + 40 * MB);   // 8 MB
  float2* rope = (float2*)(ws + 48 * MB);                 // 0.5 MB

  prep_kernel<<<8448, 256, 0, stream>>>(x, wq, wk, wv, wo, Xc, Wt, rope);
  gemm_qkv<<<dim3(16, 48), 256, 0, stream>>>(Xc, Wt, bq, bk, bv, rope, QKVb);
  attn_kernel<<<dim3(32, 32), 256, 0, stream>>>(
      QKVb, QKVb + 32ull * S_ * HD, QKVb + 64ull * S_ * HD, Ac);
  gemm_out<<<dim3(64, 16), 256, 0, stream>>>(Ac, Wt + 3ull * DM * DM, bo, (float*)d_out);
}

// Round 19
// 106.017 us; speedup vs baseline: 1.0438x; 1.0438x over previous
//
#include <hip/hip_runtime.h>
#include <hip/hip_bf16.h>

// B=2, S=2048, D=1024, H=16, HD=64. Causal MHA + RoPE.
// prep (cast+trans+rope) -> fused QKV GEMM (128x64 tile, 1536 blocks = 6/CU;
//   bf16 A via async DMA; BK=64, swizzled; RoPE fused) ->
//   MFMA flash attn v10 (R15 config: grid (32,32), 4/CU, lazy max, cvt_pk) ->
//   out GEMM (64x64 tile, 4/CU).  [R17 configuration - session best 106.05us]
// ws: Xc 8MB | Wt 8MB | QKV 24MB | Ac 8MB | rope_tab 0.5MB

#define S_ 2048
#define DM 1024
#define HD 64

typedef __attribute__((ext_vector_type(8))) short short8;   // 8 bf16
typedef __attribute__((ext_vector_type(4))) float floatx4;  // 4 f32

__device__ __forceinline__ unsigned short f2b(float x) {
  union { __hip_bfloat16 h; unsigned short u; } cv;
  cv.h = __float2bfloat16(x);
  return cv.u;
}

// pack two f32 -> dword of 2 bf16 (lo in [15:0], hi in [31:16]) in ONE VALU op
__device__ __forceinline__ unsigned cvt_pk_bf16(float lo, float hi) {
  unsigned r;
  asm("v_cvt_pk_bf16_f32 %0, %1, %2" : "=v"(r) : "v"(lo), "v"(hi));
  return r;
}

__device__ __forceinline__ void gload_lds16(const unsigned short* g, unsigned short* l) {
  typedef const __attribute__((address_space(1))) unsigned int* gp_t;
  typedef __attribute__((address_space(3))) unsigned int* lp_t;
  __builtin_amdgcn_global_load_lds((gp_t)(const void*)g, (lp_t)(void*)l, 16, 0, 0);
}

// ---------------- prep: cast x -> bf16 | transpose weights | rope table ----------------
// grid 8448 x 256: [0,4096) cast, [4096,8192) trans, [8192,8448) rope.
__global__ void prep_kernel(const float* __restrict__ x,
                            const float* __restrict__ w0, const float* __restrict__ w1,
                            const float* __restrict__ w2, const float* __restrict__ w3,
                            unsigned short* __restrict__ xc,
                            unsigned short* __restrict__ wt,
                            float2* __restrict__ rope) {
  const int bid = blockIdx.x;
  if (bid < 4096) {                       // cast: 4 f32 -> bf16 per thread
    int i = (bid * 256 + threadIdx.x) * 4;
    float4 v = *(const float4*)(x + i);
    ushort4 o;
    o.x = f2b(v.x); o.y = f2b(v.y); o.z = f2b(v.z); o.w = f2b(v.w);
    *(ushort4*)(xc + i) = o;
  } else if (bid < 8192) {                // weight transpose: Wt[n][k] = W[k][n]
    __shared__ float tile[32][33];
    const int rem = bid - 4096;
    const int z = rem >> 10;
    const int bx = (rem & 1023) & 31;
    const int by = (rem & 1023) >> 5;
    const float* W = (z == 0) ? w0 : (z == 1) ? w1 : (z == 2) ? w2 : w3;
    unsigned short* Wt = wt + (size_t)z * DM * DM;
    const int tx = threadIdx.x & 31;
    const int ty = threadIdx.x >> 5;
    const int k0 = bx * 32;
    const int c0 = by * 32;
#pragma unroll
    for (int i = 0; i < 4; ++i)
      tile[ty + i * 8][tx] = W[(size_t)(k0 + ty + i * 8) * DM + c0 + tx];
    __syncthreads();
#pragma unroll
    for (int i = 0; i < 4; ++i)
      Wt[(size_t)(c0 + ty + i * 8) * DM + k0 + tx] = f2b(tile[tx][ty + i * 8]);
  } else {                                // rope: tab[s][d2] = (cos, sin)
    int i = (bid - 8192) * 256 + threadIdx.x;  // 65536 = 2048*32
    int s = i >> 5, d2 = i & 31;
    float th = expf(-(float)d2 * (9.210340371976184f / 32.0f));
    float sn, cs;
    sincosf((float)s * th, &sn, &cs);
    rope[i] = make_float2(cs, sn);
  }
}

// ---------------- fused QKV GEMM: 128x64 tile, 1536 blocks = 6/CU ----------------
// A[4096][1024] bf16 x Wt_qkv[3072][1024]^T. grid (32,48). mat = by>>4:
// 0=Q (RoPE + 0.125*log2e), 1=K (RoPE), 2=V. bf16 out [mat][bh][s][d].
__global__ __launch_bounds__(256, 4) void gemm_qkv(
    const unsigned short* __restrict__ A, const unsigned short* __restrict__ Wt,
    const float* __restrict__ bq, const float* __restrict__ bk,
    const float* __restrict__ bv, const float2* __restrict__ rope,
    unsigned short* __restrict__ QKV) {
  __shared__ __attribute__((aligned(16))) unsigned short As[128 * 64];
  __shared__ __attribute__((aligned(16))) unsigned short Bs[64 * 64];
  const int r0 = blockIdx.x * 128;
  const int c0 = blockIdx.y * 64;
  const int t = threadIdx.x;
  const int lane = t & 63;
  const int wv = t >> 6;
  const int wr = (wv >> 1) * 64;   // 2 wave-rows x 64
  const int wc = (wv & 1) * 32;    // 2 wave-cols x 32
  const int lr = lane & 15;
  const int lg = lane >> 4;

  // staging: A rows [wv*32,+32) via 4 gloads; B rows [wv*16,+16) via 2 gloads
  const int chunk = lane >> 3;
  const int sseg = ((lane & 7) ^ chunk) * 8;
  const unsigned short* Ag = A + (size_t)(r0 + wv * 32 + chunk) * DM + sseg;
  const unsigned short* Bg = Wt + (size_t)(c0 + wv * 16 + chunk) * DM + sseg;
  unsigned short* lA = &As[wv * 32 * 64];
  unsigned short* lB = &Bs[wv * 16 * 64];

  floatx4 acc[4][2] = {};
  const int fswz = (lr & 7) << 4;

  for (int k0 = 0; k0 < DM; k0 += 64) {
#pragma unroll
    for (int j = 0; j < 4; ++j)
      gload_lds16(Ag + k0 + j * 8 * DM, lA + j * 8 * 64);
#pragma unroll
    for (int j = 0; j < 2; ++j)
      gload_lds16(Bg + k0 + j * 8 * DM, lB + j * 8 * 64);
    __syncthreads();
#pragma unroll
    for (int kk = 0; kk < 2; ++kk) {
      short8 af[4], bf[2];
#pragma unroll
      for (int m = 0; m < 4; ++m)
        af[m] = *(const short8*)((char*)As + (wr + m * 16 + lr) * 128 +
                                 ((kk * 64 + lg * 16) ^ fswz));
#pragma unroll
      for (int n = 0; n < 2; ++n)
        bf[n] = *(const short8*)((char*)Bs + (wc + n * 16 + lr) * 128 +
                                 ((kk * 64 + lg * 16) ^ fswz));
#pragma unroll
      for (int m = 0; m < 4; ++m)
#pragma unroll
        for (int n = 0; n < 2; ++n)
          acc[m][n] = __builtin_amdgcn_mfma_f32_16x16x32_bf16(af[m], bf[n], acc[m][n], 0, 0, 0);
    }
    __syncthreads();
  }

  const int mat = blockIdx.y >> 4;
  const float* bias = (mat == 0) ? bq : (mat == 1) ? bk : bv;
  const int rbase = r0 + wr + lg * 4;
  const int cbase = c0 + wc + lr;
#pragma unroll
  for (int n = 0; n < 2; ++n) {
    const int c = cbase + n * 16;
    const int cc = c & (DM - 1);
    const float bvv = bias[cc];
    const int d = c & 63;
    const int h = cc >> 6;
#pragma unroll
    for (int m = 0; m < 4; ++m) {
#pragma unroll
      for (int i = 0; i < 4; ++i) {
        const int r = rbase + m * 16 + i;
        const int s = r & (S_ - 1);
        const int b = r >> 11;
        float v = acc[m][n][i] + bvv;
        float pv = __shfl_xor(v, 1);
        if (mat < 2) {
          float2 cssn = rope[s * 32 + (d >> 1)];
          v = (d & 1) ? fmaf(v, cssn.x, pv * cssn.y) : fmaf(v, cssn.x, -pv * cssn.y);
          if (mat == 0) v *= 0.18033688011112042f;  // 0.125 * log2(e)
        }
        QKV[((size_t)((mat << 5) | (b << 4) | h) * S_ + s) * HD + d] = f2b(v);
      }
    }
  }
}

// ---------------- out projection GEMM: 64x64 tile, 1024 blocks = 4/CU ----------------
__global__ __launch_bounds__(256, 4) void gemm_out(
    const unsigned short* __restrict__ A, const unsigned short* __restrict__ Wt,
    const float* __restrict__ bias, float* __restrict__ out) {
  __shared__ __attribute__((aligned(16))) unsigned short As[64 * 64];
  __shared__ __attribute__((aligned(16))) unsigned short Bs[64 * 64];
  const int r0 = blockIdx.x * 64;
  const int c0 = blockIdx.y * 64;
  const int t = threadIdx.x;
  const int lane = t & 63;
  const int wv = t >> 6;
  const int wr = (wv >> 1) * 32;
  const int wc = (wv & 1) * 32;
  const int lr = lane & 15;
  const int lg = lane >> 4;

  const int chunk = lane >> 3;
  const int sseg = ((lane & 7) ^ chunk) * 8;
  const unsigned short* Ag = A + (size_t)(r0 + wv * 8 + chunk) * DM + sseg;
  const unsigned short* Bg = Wt + (size_t)(c0 + wv * 8 + chunk) * DM + sseg;
  unsigned short* lA = &As[wv * 8 * 64];
  unsigned short* lB = &Bs[wv * 8 * 64];

  floatx4 acc[2][2] = {};
  const int fswz = (lr & 7) << 4;

  for (int k0 = 0; k0 < DM; k0 += 64) {
#pragma unroll
    for (int j = 0; j < 2; ++j) {
      gload_lds16(Ag + k0 + j * 32 * DM, lA + j * 32 * 64);
      gload_lds16(Bg + k0 + j * 32 * DM, lB + j * 32 * 64);
    }
    __syncthreads();
#pragma unroll
    for (int kk = 0; kk < 2; ++kk) {
      short8 af[2], bf[2];
#pragma unroll
      for (int m = 0; m < 2; ++m)
        af[m] = *(const short8*)((char*)As + (wr + m * 16 + lr) * 128 +
                                 ((kk * 64 + lg * 16) ^ fswz));
#pragma unroll
      for (int n = 0; n < 2; ++n)
        bf[n] = *(const short8*)((char*)Bs + (wc + n * 16 + lr) * 128 +
                                 ((kk * 64 + lg * 16) ^ fswz));
#pragma unroll
      for (int m = 0; m < 2; ++m)
#pragma unroll
        for (int n = 0; n < 2; ++n)
          acc[m][n] = __builtin_amdgcn_mfma_f32_16x16x32_bf16(af[m], bf[n], acc[m][n], 0, 0, 0);
    }
    __syncthreads();
  }

  const int rbase = r0 + wr + lg * 4;
  const int cbase = c0 + wc + lr;
#pragma unroll
  for (int n = 0; n < 2; ++n) {
    const int c = cbase + n * 16;
    const float bvv = bias[c];
#pragma unroll
    for (int m = 0; m < 2; ++m) {
#pragma unroll
      for (int i = 0; i < 4; ++i) {
        const int r = rbase + m * 16 + i;
        out[(size_t)r * DM + c] = acc[m][n][i] + bvv;
      }
    }
  }
}

// ---------------- MFMA flash attention v10 (R15 config): lazy cross-lane max ----------------
#define ATTN_STEP(TT, BUF, KLA, KLB)                                           \
  do {                                                                         \
    { /* (a) V regs (tile TT) -> Vs[BUF], transposed+paired */                 \
      char* Vb = (char*)Vs[BUF];                                               \
      const unsigned* ua = (const unsigned*)&va;                               \
      const unsigned* ub = (const unsigned*)&vb;                               \
      _Pragma("unroll") for (int j = 0; j < 8; ++j) {                          \
        unsigned pkv = __builtin_amdgcn_perm(                                  \
            ub[j >> 1], ua[j >> 1], (j & 1) ? 0x07060302u : 0x05040100u);      \
        *(unsigned*)(Vb + (oct * 8 + j) * 128 + ((4 * kp) ^ (j << 4))) = pkv;  \
      }                                                                        \
    }                                                                          \
    if ((TT) < qt) { /* (b) V prefetch (TT+1) */                               \
      va = *(const short8*)(Vpref);                                            \
      vb = *(const short8*)(Vpref + 64);                                       \
      Vpref += 4096;                                                           \
    }                                                                          \
    /* (c) barrier: LDS drain only, VMEM stays in flight */                    \
    asm volatile("s_waitcnt lgkmcnt(0)" ::: "memory");                         \
    __builtin_amdgcn_s_barrier();                                              \
    /* (d) wait K-DMA(TT); 2 newer V loads may remain in flight */             \
    if ((TT) < qt) asm volatile("s_waitcnt vmcnt(2)" ::: "memory");            \
    else           asm volatile("s_waitcnt vmcnt(0)" ::: "memory");            \
    __builtin_amdgcn_sched_barrier(0);                                         \
    if ((TT) < qt) { /* (e) K DMA for TT+1 -> other buffer */                  \
      gload_lds16(Kpref, KLA);                                                 \
      gload_lds16(Kpref + 2048, KLB);                                          \
      Kpref += 4096;                                                           \
    }                                                                          \
    /* (f) S^T = K Q^T : s[n][i] = S[key=n*16+lg*4+i][q=lr] */                 \
    floatx4 s[4] = {};                                                         \
    __builtin_amdgcn_s_setprio(1);                                             \
    _Pragma("unroll") for (int kk = 0; kk < 2; ++kk) {                         \
      _Pragma("unroll") for (int n = 0; n < 4; ++n) {                          \
        int r = n * 16 + lr;                                                   \
        short8 kf = *(const short8*)((char*)Ks[BUF] + r * 128 +                \
                                     ((kk * 64 + lg * 16) ^ ((r & 7) << 4)));  \
        s[n] = __builtin_amdgcn_mfma_f32_16x16x32_bf16(kf, qf[kk], s[n], 0, 0, 0); \
      }                                                                        \
    }                                                                          \
    __builtin_amdgcn_s_setprio(0);                                             \
    if ((TT) == qt) {                                                          \
      _Pragma("unroll") for (int n = 0; n < 4; ++n)                            \
        _Pragma("unroll") for (int i = 0; i < 4; ++i)                          \
          if (n * 16 + lg * 4 + i > qin) s[n][i] = -1e30f;                     \
    }                                                                          \
    /* in-lane 16-max only (max3-friendly triples) */                          \
    float ta = fmaxf(fmaxf(s[0][0], s[0][1]), s[0][2]);                        \
    float tb = fmaxf(fmaxf(s[0][3], s[1][0]), s[1][1]);                        \
    float tc = fmaxf(fmaxf(s[1][2], s[1][3]), s[2][0]);                        \
    float td = fmaxf(fmaxf(s[2][1], s[2][2]), s[2][3]);                        \
    float te = fmaxf(fmaxf(s[3][0], s[3][1]), s[3][2]);                        \
    float tm = fmaxf(fmaxf(ta, tb), tc);                                       \
    tm = fmaxf(fmaxf(tm, td), te);                                             \
    tm = fmaxf(tm, s[3][3]);                                                   \
    /* lazy max: cross-lane shuffles + rescale only when triggered */          \
    if (__any(tm > m + 8.f)) {                                                 \
      tm = fmaxf(tm, __shfl_xor(tm, 16));                                      \
      tm = fmaxf(tm, __shfl_xor(tm, 32));                                      \
      const float mn = fmaxf(m, tm);                                           \
      const float al = exp2f(m - mn);                                          \
      m = mn;                                                                  \
      lsum *= al;                                                              \
      _Pragma("unroll") for (int dd = 0; dd < 4; ++dd) o[dd] *= al;            \
    }                                                                          \
    float ps = 0.f;                                                            \
    _Pragma("unroll") for (int n = 0; n < 4; ++n) {                            \
      _Pragma("unroll") for (int i = 0; i < 4; ++i) {                          \
        float p = exp2f(s[n][i] - m);                                          \
        s[n][i] = p;                                                           \
        ps += p;                                                               \
      }                                                                        \
    }                                                                          \
    lsum += ps;                                                                \
    /* P^T rows into Ps[w] via cvt_pk (1 VALU per pair) */                     \
    _Pragma("unroll") for (int n = 0; n < 4; ++n) {                            \
      _Pragma("unroll") for (int hh = 0; hh < 2; ++hh) {                       \
        unsigned pk = cvt_pk_bf16(s[n][2 * hh], s[n][2 * hh + 1]);             \
        *(unsigned*)(Pw + lr * 128 +                                           \
                     (((n * 16 + lg * 4 + 2 * hh) * 2) ^ pswz)) = pk;          \
      }                                                                        \
    }                                                                          \
    short8 pb[2];                                                              \
    _Pragma("unroll") for (int kk = 0; kk < 2; ++kk)                           \
      pb[kk] = *(const short8*)(Pw + lr * 128 + ((kk * 64 + lg * 16) ^ pswz)); \
    __builtin_amdgcn_s_setprio(1);                                             \
    _Pragma("unroll") for (int kk = 0; kk < 2; ++kk)                           \
      _Pragma("unroll") for (int dd = 0; dd < 4; ++dd) {                       \
        int d = dd * 16 + lr;                                                  \
        short8 vbf = *(const short8*)((char*)Vs[BUF] + d * 128 +               \
                                      ((kk * 64 + lg * 16) ^ ((d & 7) << 4))); \
        o[dd] = __builtin_amdgcn_mfma_f32_16x16x32_bf16(vbf, pb[kk], o[dd], 0, 0, 0); \
      }                                                                        \
    __builtin_amdgcn_s_setprio(0);                                             \
  } while (0)

__global__ __launch_bounds__(256, 4) void attn_kernel(
    const unsigned short* __restrict__ Q, const unsigned short* __restrict__ K,
    const unsigned short* __restrict__ V, unsigned short* __restrict__ AttnC) {
  __shared__ __attribute__((aligned(16))) unsigned short Ks[2][64 * 64];
  __shared__ __attribute__((aligned(16))) unsigned short Vs[2][64 * 64];
  __shared__ __attribute__((aligned(16))) unsigned short Ps[4][16 * 64];

  const int bh = blockIdx.x;
  const int qt = 31 - (int)blockIdx.y;  // LPT: big blocks first
  const int tid = threadIdx.x;
  const int w = tid >> 6;
  const int l = tid & 63;
  const int lg = l >> 4;
  const int lr = l & 15;
  const size_t base = (size_t)bh * S_ * HD;
  const int qin = w * 16 + lr;

  // Q as B-frag: B[k][q=lr] = Q[q][k], k = kk*32 + lg*8 + j
  short8 qf[2];
  {
    const unsigned short* Qrow =
        Q + base + (size_t)(qt * 64 + w * 16 + lr) * HD + lg * 8;
    qf[0] = *(const short8*)(Qrow);
    qf[1] = *(const short8*)(Qrow + 32);
  }

  floatx4 o[4] = {};
  float m = -1e30f, lsum = 0.f;

  // K staging: pre-swizzled global source -> linear LDS via global_load_lds.
  const int krow = tid >> 3;
  const int kseg = tid & 7;
  const unsigned short* Kpref = K + base + krow * 64 + ((kseg ^ (krow & 7)) * 8);
  unsigned short* const kld0a = &Ks[0][w * 512];
  unsigned short* const kld0b = &Ks[0][2048 + w * 512];
  unsigned short* const kld1a = &Ks[1][w * 512];
  unsigned short* const kld1b = &Ks[1][2048 + w * 512];

  // V staging roles: key-pair 2kp,2kp+1, dims oct*8..+8
  const int oct = tid >> 5;
  const int kp = tid & 31;
  const unsigned short* Vpref = V + base + 2 * kp * 64 + oct * 8;

  // prologue: V regs first, then K DMA (so V-use waits vmcnt(2), not 0)
  short8 va = *(const short8*)(Vpref);
  short8 vb = *(const short8*)(Vpref + 64);
  Vpref += 4096;
  gload_lds16(Kpref, kld0a);
  gload_lds16(Kpref + 2048, kld0b);
  Kpref += 4096;

  char* const Pw = (char*)Ps[w];
  const int pswz = (lr & 7) << 4;

  int t = 0;
#pragma unroll 1
  for (; t + 1 <= qt; t += 2) {
    ATTN_STEP(t, 0, kld1a, kld1b);
    ATTN_STEP(t + 1, 1, kld0a, kld0b);
  }
  if (t <= qt) ATTN_STEP(t, 0, kld1a, kld1b);

  // reduce lsum across the 4 lg-partials, write O[q=lr][d=dd*16+lg*4+i]
  lsum += __shfl_xor(lsum, 16);
  lsum += __shfl_xor(lsum, 32);
  const float inv = 1.f / lsum;
  unsigned short* orow =
      AttnC + (size_t)((bh >> 4) * S_ + qt * 64 + w * 16 + lr) * DM + (bh & 15) * HD;
#pragma unroll
  for (int dd = 0; dd < 4; ++dd) {
    unsigned w0 = cvt_pk_bf16(o[dd][0] * inv, o[dd][1] * inv);
    unsigned w1 = cvt_pk_bf16(o[dd][2] * inv, o[dd][3] * inv);
    *(uint2*)(orow + dd * 16 + lg * 4) = make_uint2(w0, w1);
  }
}

extern "C" void kernel_launch(void* const* d_in, const int* in_sizes, int n_in,
                              void* d_out, int out_size, void* d_ws, size_t ws_size,
                              hipStream_t stream) {
  const float* x = (const float*)d_in[0];
  const float* wq = (const float*)d_in[2];
  const float* bq = (const float*)d_in[3];
  const float* wk = (const float*)d_in[4];
  const float* bk = (const float*)d_in[5];
  const float* wv = (const float*)d_in[6];
  const float* bv = (const float*)d_in[7];
  const float* wo = (const float*)d_in[8];
  const float* bo = (const float*)d_in[9];

  char* ws = (char*)d_ws;
  const size_t MB = 1024ull * 1024ull;
  unsigned short* Xc = (unsigned short*)(ws);             // 8 MB
  unsigned short* Wt = (unsigned short*)(ws + 8 * MB);    // 4 x 2 MB
  unsigned short* QKVb = (unsigned short*)(ws + 16 * MB); // 24 MB
  unsigned short* Ac = (unsigned short*)(ws + 40 * MB);   // 8 MB
  float2* rope = (float2*)(ws + 48 * MB);                 // 0.5 MB

  prep_kernel<<<8448, 256, 0, stream>>>(x, wq, wk, wv, wo, Xc, Wt, rope);
  gemm_qkv<<<dim3(32, 48), 256, 0, stream>>>(Xc, Wt, bq, bk, bv, rope, QKVb);
  attn_kernel<<<dim3(32, 32), 256, 0, stream>>>(
      QKVb, QKVb + 32ull * S_ * HD, QKVb + 64ull * S_ * HD, Ac);
  gemm_out<<<dim3(64, 16), 256, 0, stream>>>(Ac, Wt + 3ull * DM * DM, bo, (float*)d_out);
}

// Round 22
// 105.895 us; speedup vs baseline: 1.0450x; 1.0011x over previous
//
#include <hip/hip_runtime.h>
#include <hip/hip_bf16.h>

// B=2, S=2048, D=1024, H=16, HD=64. Causal MHA + RoPE.
// prep (cast+trans+rope) -> fused QKV GEMM (128x64 tile, 1536 blocks = 6/CU;
//   bf16 A via async DMA; BK=64, swizzled; RoPE fused) ->
//   MFMA flash attn v10 (grid (32,32), 4/CU, lazy max, cvt_pk, counted vmcnt)
//   -> out GEMM (64x64 tile, 4/CU).  [verified config: 106.0 us, R17/R19]
// ws: Xc 8MB | Wt 8MB | QKV 24MB | Ac 8MB | rope_tab 0.5MB

#define S_ 2048
#define DM 1024
#define HD 64

typedef __attribute__((ext_vector_type(8))) short short8;   // 8 bf16
typedef __attribute__((ext_vector_type(4))) float floatx4;  // 4 f32

__device__ __forceinline__ unsigned short f2b(float x) {
  union { __hip_bfloat16 h; unsigned short u; } cv;
  cv.h = __float2bfloat16(x);
  return cv.u;
}

// pack two f32 -> dword of 2 bf16 (lo in [15:0], hi in [31:16]) in ONE VALU op
__device__ __forceinline__ unsigned cvt_pk_bf16(float lo, float hi) {
  unsigned r;
  asm("v_cvt_pk_bf16_f32 %0, %1, %2" : "=v"(r) : "v"(lo), "v"(hi));
  return r;
}

__device__ __forceinline__ void gload_lds16(const unsigned short* g, unsigned short* l) {
  typedef const __attribute__((address_space(1))) unsigned int* gp_t;
  typedef __attribute__((address_space(3))) unsigned int* lp_t;
  __builtin_amdgcn_global_load_lds((gp_t)(const void*)g, (lp_t)(void*)l, 16, 0, 0);
}

// ---------------- prep: cast x -> bf16 | transpose weights | rope table ----------------
// grid 8448 x 256: [0,4096) cast, [4096,8192) trans, [8192,8448) rope.
__global__ void prep_kernel(const float* __restrict__ x,
                            const float* __restrict__ w0, const float* __restrict__ w1,
                            const float* __restrict__ w2, const float* __restrict__ w3,
                            unsigned short* __restrict__ xc,
                            unsigned short* __restrict__ wt,
                            float2* __restrict__ rope) {
  const int bid = blockIdx.x;
  if (bid < 4096) {                       // cast: 4 f32 -> bf16 per thread
    int i = (bid * 256 + threadIdx.x) * 4;
    float4 v = *(const float4*)(x + i);
    ushort4 o;
    o.x = f2b(v.x); o.y = f2b(v.y); o.z = f2b(v.z); o.w = f2b(v.w);
    *(ushort4*)(xc + i) = o;
  } else if (bid < 8192) {                // weight transpose: Wt[n][k] = W[k][n]
    __shared__ float tile[32][33];
    const int rem = bid - 4096;
    const int z = rem >> 10;
    const int bx = (rem & 1023) & 31;
    const int by = (rem & 1023) >> 5;
    const float* W = (z == 0) ? w0 : (z == 1) ? w1 : (z == 2) ? w2 : w3;
    unsigned short* Wt = wt + (size_t)z * DM * DM;
    const int tx = threadIdx.x & 31;
    const int ty = threadIdx.x >> 5;
    const int k0 = bx * 32;
    const int c0 = by * 32;
#pragma unroll
    for (int i = 0; i < 4; ++i)
      tile[ty + i * 8][tx] = W[(size_t)(k0 + ty + i * 8) * DM + c0 + tx];
    __syncthreads();
#pragma unroll
    for (int i = 0; i < 4; ++i)
      Wt[(size_t)(c0 + ty + i * 8) * DM + k0 + tx] = f2b(tile[tx][ty + i * 8]);
  } else {                                // rope: tab[s][d2] = (cos, sin)
    int i = (bid - 8192) * 256 + threadIdx.x;  // 65536 = 2048*32
    int s = i >> 5, d2 = i & 31;
    float th = expf(-(float)d2 * (9.210340371976184f / 32.0f));
    float sn, cs;
    sincosf((float)s * th, &sn, &cs);
    rope[i] = make_float2(cs, sn);
  }
}

// ---------------- fused QKV GEMM: 128x64 tile, 1536 blocks = 6/CU ----------------
// A[4096][1024] bf16 x Wt_qkv[3072][1024]^T. grid (32,48). mat = by>>4:
// 0=Q (RoPE + 0.125*log2e), 1=K (RoPE), 2=V. bf16 out [mat][bh][s][d].
__global__ __launch_bounds__(256, 4) void gemm_qkv(
    const unsigned short* __restrict__ A, const unsigned short* __restrict__ Wt,
    const float* __restrict__ bq, const float* __restrict__ bk,
    const float* __restrict__ bv, const float2* __restrict__ rope,
    unsigned short* __restrict__ QKV) {
  __shared__ __attribute__((aligned(16))) unsigned short As[128 * 64];
  __shared__ __attribute__((aligned(16))) unsigned short Bs[64 * 64];
  const int r0 = blockIdx.x * 128;
  const int c0 = blockIdx.y * 64;
  const int t = threadIdx.x;
  const int lane = t & 63;
  const int wv = t >> 6;
  const int wr = (wv >> 1) * 64;   // 2 wave-rows x 64
  const int wc = (wv & 1) * 32;    // 2 wave-cols x 32
  const int lr = lane & 15;
  const int lg = lane >> 4;

  // staging: A rows [wv*32,+32) via 4 gloads; B rows [wv*16,+16) via 2 gloads
  const int chunk = lane >> 3;
  const int sseg = ((lane & 7) ^ chunk) * 8;
  const unsigned short* Ag = A + (size_t)(r0 + wv * 32 + chunk) * DM + sseg;
  const unsigned short* Bg = Wt + (size_t)(c0 + wv * 16 + chunk) * DM + sseg;
  unsigned short* lA = &As[wv * 32 * 64];
  unsigned short* lB = &Bs[wv * 16 * 64];

  floatx4 acc[4][2] = {};
  const int fswz = (lr & 7) << 4;

  for (int k0 = 0; k0 < DM; k0 += 64) {
#pragma unroll
    for (int j = 0; j < 4; ++j)
      gload_lds16(Ag + k0 + j * 8 * DM, lA + j * 8 * 64);
#pragma unroll
    for (int j = 0; j < 2; ++j)
      gload_lds16(Bg + k0 + j * 8 * DM, lB + j * 8 * 64);
    __syncthreads();
#pragma unroll
    for (int kk = 0; kk < 2; ++kk) {
      short8 af[4], bf[2];
#pragma unroll
      for (int m = 0; m < 4; ++m)
        af[m] = *(const short8*)((char*)As + (wr + m * 16 + lr) * 128 +
                                 ((kk * 64 + lg * 16) ^ fswz));
#pragma unroll
      for (int n = 0; n < 2; ++n)
        bf[n] = *(const short8*)((char*)Bs + (wc + n * 16 + lr) * 128 +
                                 ((kk * 64 + lg * 16) ^ fswz));
#pragma unroll
      for (int m = 0; m < 4; ++m)
#pragma unroll
        for (int n = 0; n < 2; ++n)
          acc[m][n] = __builtin_amdgcn_mfma_f32_16x16x32_bf16(af[m], bf[n], acc[m][n], 0, 0, 0);
    }
    __syncthreads();
  }

  const int mat = blockIdx.y >> 4;
  const float* bias = (mat == 0) ? bq : (mat == 1) ? bk : bv;
  const int rbase = r0 + wr + lg * 4;
  const int cbase = c0 + wc + lr;
#pragma unroll
  for (int n = 0; n < 2; ++n) {
    const int c = cbase + n * 16;
    const int cc = c & (DM - 1);
    const float bvv = bias[cc];
    const int d = c & 63;
    const int h = cc >> 6;
#pragma unroll
    for (int m = 0; m < 4; ++m) {
#pragma unroll
      for (int i = 0; i < 4; ++i) {
        const int r = rbase + m * 16 + i;
        const int s = r & (S_ - 1);
        const int b = r >> 11;
        float v = acc[m][n][i] + bvv;
        float pv = __shfl_xor(v, 1);
        if (mat < 2) {
          float2 cssn = rope[s * 32 + (d >> 1)];
          v = (d & 1) ? fmaf(v, cssn.x, pv * cssn.y) : fmaf(v, cssn.x, -pv * cssn.y);
          if (mat == 0) v *= 0.18033688011112042f;  // 0.125 * log2(e)
        }
        QKV[((size_t)((mat << 5) | (b << 4) | h) * S_ + s) * HD + d] = f2b(v);
      }
    }
  }
}

// ---------------- out projection GEMM: 64x64 tile, 1024 blocks = 4/CU ----------------
__global__ __launch_bounds__(256, 4) void gemm_out(
    const unsigned short* __restrict__ A, const unsigned short* __restrict__ Wt,
    const float* __restrict__ bias, float* __restrict__ out) {
  __shared__ __attribute__((aligned(16))) unsigned short As[64 * 64];
  __shared__ __attribute__((aligned(16))) unsigned short Bs[64 * 64];
  const int r0 = blockIdx.x * 64;
  const int c0 = blockIdx.y * 64;
  const int t = threadIdx.x;
  const int lane = t & 63;
  const int wv = t >> 6;
  const int wr = (wv >> 1) * 32;
  const int wc = (wv & 1) * 32;
  const int lr = lane & 15;
  const int lg = lane >> 4;

  const int chunk = lane >> 3;
  const int sseg = ((lane & 7) ^ chunk) * 8;
  const unsigned short* Ag = A + (size_t)(r0 + wv * 8 + chunk) * DM + sseg;
  const unsigned short* Bg = Wt + (size_t)(c0 + wv * 8 + chunk) * DM + sseg;
  unsigned short* lA = &As[wv * 8 * 64];
  unsigned short* lB = &Bs[wv * 8 * 64];

  floatx4 acc[2][2] = {};
  const int fswz = (lr & 7) << 4;

  for (int k0 = 0; k0 < DM; k0 += 64) {
#pragma unroll
    for (int j = 0; j < 2; ++j) {
      gload_lds16(Ag + k0 + j * 32 * DM, lA + j * 32 * 64);
      gload_lds16(Bg + k0 + j * 32 * DM, lB + j * 32 * 64);
    }
    __syncthreads();
#pragma unroll
    for (int kk = 0; kk < 2; ++kk) {
      short8 af[2], bf[2];
#pragma unroll
      for (int m = 0; m < 2; ++m)
        af[m] = *(const short8*)((char*)As + (wr + m * 16 + lr) * 128 +
                                 ((kk * 64 + lg * 16) ^ fswz));
#pragma unroll
      for (int n = 0; n < 2; ++n)
        bf[n] = *(const short8*)((char*)Bs + (wc + n * 16 + lr) * 128 +
                                 ((kk * 64 + lg * 16) ^ fswz));
#pragma unroll
      for (int m = 0; m < 2; ++m)
#pragma unroll
        for (int n = 0; n < 2; ++n)
          acc[m][n] = __builtin_amdgcn_mfma_f32_16x16x32_bf16(af[m], bf[n], acc[m][n], 0, 0, 0);
    }
    __syncthreads();
  }

  const int rbase = r0 + wr + lg * 4;
  const int cbase = c0 + wc + lr;
#pragma unroll
  for (int n = 0; n < 2; ++n) {
    const int c = cbase + n * 16;
    const float bvv = bias[c];
#pragma unroll
    for (int m = 0; m < 2; ++m) {
#pragma unroll
      for (int i = 0; i < 4; ++i) {
        const int r = rbase + m * 16 + i;
        out[(size_t)r * DM + c] = acc[m][n][i] + bvv;
      }
    }
  }
}

// ---------------- MFMA flash attention v10: lazy cross-lane max ----------------
#define ATTN_STEP(TT, BUF, KLA, KLB)                                           \
  do {                                                                         \
    { /* (a) V regs (tile TT) -> Vs[BUF], transposed+paired */                 \
      char* Vb = (char*)Vs[BUF];                                               \
      const unsigned* ua = (const unsigned*)&va;                               \
      const unsigned* ub = (const unsigned*)&vb;                               \
      _Pragma("unroll") for (int j = 0; j < 8; ++j) {                          \
        unsigned pkv = __builtin_amdgcn_perm(                                  \
            ub[j >> 1], ua[j >> 1], (j & 1) ? 0x07060302u : 0x05040100u);      \
        *(unsigned*)(Vb + (oct * 8 + j) * 128 + ((4 * kp) ^ (j << 4))) = pkv;  \
      }                                                                        \
    }                                                                          \
    if ((TT) < qt) { /* (b) V prefetch (TT+1) */                               \
      va = *(const short8*)(Vpref);                                            \
      vb = *(const short8*)(Vpref + 64);                                       \
      Vpref += 4096;                                                           \
    }                                                                          \
    /* (c) barrier: LDS drain only, VMEM stays in flight */                    \
    asm volatile("s_waitcnt lgkmcnt(0)" ::: "memory");                         \
    __builtin_amdgcn_s_barrier();                                              \
    /* (d) wait K-DMA(TT); 2 newer V loads may remain in flight */             \
    if ((TT) < qt) asm volatile("s_waitcnt vmcnt(2)" ::: "memory");            \
    else           asm volatile("s_waitcnt vmcnt(0)" ::: "memory");            \
    __builtin_amdgcn_sched_barrier(0);                                         \
    if ((TT) < qt) { /* (e) K DMA for TT+1 -> other buffer */                  \
      gload_lds16(Kpref, KLA);                                                 \
      gload_lds16(Kpref + 2048, KLB);                                          \
      Kpref += 4096;                                                           \
    }                                                                          \
    /* (f) S^T = K Q^T : s[n][i] = S[key=n*16+lg*4+i][q=lr] */                 \
    floatx4 s[4] = {};                                                         \
    __builtin_amdgcn_s_setprio(1);                                             \
    _Pragma("unroll") for (int kk = 0; kk < 2; ++kk) {                         \
      _Pragma("unroll") for (int n = 0; n < 4; ++n) {                          \
        int r = n * 16 + lr;                                                   \
        short8 kf = *(const short8*)((char*)Ks[BUF] + r * 128 +                \
                                     ((kk * 64 + lg * 16) ^ ((r & 7) << 4)));  \
        s[n] = __builtin_amdgcn_mfma_f32_16x16x32_bf16(kf, qf[kk], s[n], 0, 0, 0); \
      }                                                                        \
    }                                                                          \
    __builtin_amdgcn_s_setprio(0);                                             \
    if ((TT) == qt) {                                                          \
      _Pragma("unroll") for (int n = 0; n < 4; ++n)                            \
        _Pragma("unroll") for (int i = 0; i < 4; ++i)                          \
          if (n * 16 + lg * 4 + i > qin) s[n][i] = -1e30f;                     \
    }                                                                          \
    /* in-lane 16-max only (max3-friendly triples) */                          \
    float ta = fmaxf(fmaxf(s[0][0], s[0][1]), s[0][2]);                        \
    float tb = fmaxf(fmaxf(s[0][3], s[1][0]), s[1][1]);                        \
    float tc = fmaxf(fmaxf(s[1][2], s[1][3]), s[2][0]);                        \
    float td = fmaxf(fmaxf(s[2][1], s[2][2]), s[2][3]);                        \
    float te = fmaxf(fmaxf(s[3][0], s[3][1]), s[3][2]);                        \
    float tm = fmaxf(fmaxf(ta, tb), tc);                                       \
    tm = fmaxf(fmaxf(tm, td), te);                                             \
    tm = fmaxf(tm, s[3][3]);                                                   \
    /* lazy max: cross-lane shuffles + rescale only when triggered */          \
    if (__any(tm > m + 8.f)) {                                                 \
      tm = fmaxf(tm, __shfl_xor(tm, 16));                                      \
      tm = fmaxf(tm, __shfl_xor(tm, 32));                                      \
      const float mn = fmaxf(m, tm);                                           \
      const float al = exp2f(m - mn);                                          \
      m = mn;                                                                  \
      lsum *= al;                                                              \
      _Pragma("unroll") for (int dd = 0; dd < 4; ++dd) o[dd] *= al;            \
    }                                                                          \
    float ps = 0.f;                                                            \
    _Pragma("unroll") for (int n = 0; n < 4; ++n) {                            \
      _Pragma("unroll") for (int i = 0; i < 4; ++i) {                          \
        float p = exp2f(s[n][i] - m);                                          \
        s[n][i] = p;                                                           \
        ps += p;                                                               \
      }                                                                        \
    }                                                                          \
    lsum += ps;                                                                \
    /* P^T rows into Ps[w] via cvt_pk (1 VALU per pair) */                     \
    _Pragma("unroll") for (int n = 0; n < 4; ++n) {                            \
      _Pragma("unroll") for (int hh = 0; hh < 2; ++hh) {                       \
        unsigned pk = cvt_pk_bf16(s[n][2 * hh], s[n][2 * hh + 1]);             \
        *(unsigned*)(Pw + lr * 128 +                                           \
                     (((n * 16 + lg * 4 + 2 * hh) * 2) ^ pswz)) = pk;          \
      }                                                                        \
    }                                                                          \
    short8 pb[2];                                                              \
    _Pragma("unroll") for (int kk = 0; kk < 2; ++kk)                           \
      pb[kk] = *(const short8*)(Pw + lr * 128 + ((kk * 64 + lg * 16) ^ pswz)); \
    __builtin_amdgcn_s_setprio(1);                                             \
    _Pragma("unroll") for (int kk = 0; kk < 2; ++kk)                           \
      _Pragma("unroll") for (int dd = 0; dd < 4; ++dd) {                       \
        int d = dd * 16 + lr;                                                  \
        short8 vbf = *(const short8*)((char*)Vs[BUF] + d * 128 +               \
                                      ((kk * 64 + lg * 16) ^ ((d & 7) << 4))); \
        o[dd] = __builtin_amdgcn_mfma_f32_16x16x32_bf16(vbf, pb[kk], o[dd], 0, 0, 0); \
      }                                                                        \
    __builtin_amdgcn_s_setprio(0);                                             \
  } while (0)

__global__ __launch_bounds__(256, 4) void attn_kernel(
    const unsigned short* __restrict__ Q, const unsigned short* __restrict__ K,
    const unsigned short* __restrict__ V, unsigned short* __restrict__ AttnC) {
  __shared__ __attribute__((aligned(16))) unsigned short Ks[2][64 * 64];
  __shared__ __attribute__((aligned(16))) unsigned short Vs[2][64 * 64];
  __shared__ __attribute__((aligned(16))) unsigned short Ps[4][16 * 64];

  const int bh = blockIdx.x;
  const int qt = 31 - (int)blockIdx.y;  // LPT: big blocks first
  const int tid = threadIdx.x;
  const int w = tid >> 6;
  const int l = tid & 63;
  const int lg = l >> 4;
  const int lr = l & 15;
  const size_t base = (size_t)bh * S_ * HD;
  const int qin = w * 16 + lr;

  // Q as B-frag: B[k][q=lr] = Q[q][k], k = kk*32 + lg*8 + j
  short8 qf[2];
  {
    const unsigned short* Qrow =
        Q + base + (size_t)(qt * 64 + w * 16 + lr) * HD + lg * 8;
    qf[0] = *(const short8*)(Qrow);
    qf[1] = *(const short8*)(Qrow + 32);
  }

  floatx4 o[4] = {};
  float m = -1e30f, lsum = 0.f;

  // K staging: pre-swizzled global source -> linear LDS via global_load_lds.
  const int krow = tid >> 3;
  const int kseg = tid & 7;
  const unsigned short* Kpref = K + base + krow * 64 + ((kseg ^ (krow & 7)) * 8);
  unsigned short* const kld0a = &Ks[0][w * 512];
  unsigned short* const kld0b = &Ks[0][2048 + w * 512];
  unsigned short* const kld1a = &Ks[1][w * 512];
  unsigned short* const kld1b = &Ks[1][2048 + w * 512];

  // V staging roles: key-pair 2kp,2kp+1, dims oct*8..+8
  const int oct = tid >> 5;
  const int kp = tid & 31;
  const unsigned short* Vpref = V + base + 2 * kp * 64 + oct * 8;

  // prologue: V regs first, then K DMA (so V-use waits vmcnt(2), not 0)
  short8 va = *(const short8*)(Vpref);
  short8 vb = *(const short8*)(Vpref + 64);
  Vpref += 4096;
  gload_lds16(Kpref, kld0a);
  gload_lds16(Kpref + 2048, kld0b);
  Kpref += 4096;

  char* const Pw = (char*)Ps[w];
  const int pswz = (lr & 7) << 4;

  int t = 0;
#pragma unroll 1
  for (; t + 1 <= qt; t += 2) {
    ATTN_STEP(t, 0, kld1a, kld1b);
    ATTN_STEP(t + 1, 1, kld0a, kld0b);
  }
  if (t <= qt) ATTN_STEP(t, 0, kld1a, kld1b);

  // reduce lsum across the 4 lg-partials, write O[q=lr][d=dd*16+lg*4+i]
  lsum += __shfl_xor(lsum, 16);
  lsum += __shfl_xor(lsum, 32);
  const float inv = 1.f / lsum;
  unsigned short* orow =
      AttnC + (size_t)((bh >> 4) * S_ + qt * 64 + w * 16 + lr) * DM + (bh & 15) * HD;
#pragma unroll
  for (int dd = 0; dd < 4; ++dd) {
    unsigned w0 = cvt_pk_bf16(o[dd][0] * inv, o[dd][1] * inv);
    unsigned w1 = cvt_pk_bf16(o[dd][2] * inv, o[dd][3] * inv);
    *(uint2*)(orow + dd * 16 + lg * 4) = make_uint2(w0, w1);
  }
}

extern "C" void kernel_launch(void* const* d_in, const int* in_sizes, int n_in,
                              void* d_out, int out_size, void* d_ws, size_t ws_size,
                              hipStream_t stream) {
  const float* x = (const float*)d_in[0];
  const float* wq = (const float*)d_in[2];
  const float* bq = (const float*)d_in[3];
  const float* wk = (const float*)d_in[4];
  const float* bk = (const float*)d_in[5];
  const float* wv = (const float*)d_in[6];
  const float* bv = (const float*)d_in[7];
  const float* wo = (const float*)d_in[8];
  const float* bo = (const float*)d_in[9];

  char* ws = (char*)d_ws;
  const size_t MB = 1024ull * 1024ull;
  unsigned short* Xc = (unsigned short*)(ws);             // 8 MB
  unsigned short* Wt = (unsigned short*)(ws + 8 * MB);    // 4 x 2 MB
  unsigned short* QKVb = (unsigned short*)(ws + 16 * MB); // 24 MB
  unsigned short* Ac = (unsigned short*)(ws + 40 * MB);   // 8 MB
  float2* rope = (float2*)(ws + 48 * MB);                 // 0.5 MB

  prep_kernel<<<8448, 256, 0, stream>>>(x, wq, wk, wv, wo, Xc, Wt, rope);
  gemm_qkv<<<dim3(32, 48), 256, 0, stream>>>(Xc, Wt, bq, bk, bv, rope, QKVb);
  attn_kernel<<<dim3(32, 32), 256, 0, stream>>>(
      QKVb, QKVb + 32ull * S_ * HD, QKVb + 64ull * S_ * HD, Ac);
  gemm_out<<<dim3(64, 16), 256, 0, stream>>>(Ac, Wt + 3ull * DM * DM, bo, (float*)d_out);
}

// Round 23
// 104.166 us; speedup vs baseline: 1.0624x; 1.0166x over previous
//
#include <hip/hip_runtime.h>
#include <hip/hip_bf16.h>

// B=2, S=2048, D=1024, H=16, HD=64. Causal MHA + RoPE.
// prep (cast+trans+rope) -> fused QKV GEMM (128x64, 6/CU; RoPE fused; V written
//   TRANSPOSED VT[bh][d][s]) -> MFMA flash attn v12b (pure-DMA K+V staging,
//   prologue drain+barrier fixes tile-0 race, vmcnt(4) pipeline, lazy max,
//   cvt_pk) -> out GEMM (64x64, 4/CU).
// ws: Xc 8MB | Wt 8MB | Q 8MB | K 8MB | VT 8MB | Ac 8MB | rope_tab 0.5MB

#define S_ 2048
#define DM 1024
#define HD 64

typedef __attribute__((ext_vector_type(8))) short short8;   // 8 bf16
typedef __attribute__((ext_vector_type(4))) float floatx4;  // 4 f32

__device__ __forceinline__ unsigned short f2b(float x) {
  union { __hip_bfloat16 h; unsigned short u; } cv;
  cv.h = __float2bfloat16(x);
  return cv.u;
}

// pack two f32 -> dword of 2 bf16 (lo in [15:0], hi in [31:16]) in ONE VALU op
__device__ __forceinline__ unsigned cvt_pk_bf16(float lo, float hi) {
  unsigned r;
  asm("v_cvt_pk_bf16_f32 %0, %1, %2" : "=v"(r) : "v"(lo), "v"(hi));
  return r;
}

__device__ __forceinline__ void gload_lds16(const unsigned short* g, unsigned short* l) {
  typedef const __attribute__((address_space(1))) unsigned int* gp_t;
  typedef __attribute__((address_space(3))) unsigned int* lp_t;
  __builtin_amdgcn_global_load_lds((gp_t)(const void*)g, (lp_t)(void*)l, 16, 0, 0);
}

// ---------------- prep: cast x -> bf16 | transpose weights | rope table ----------------
// grid 8448 x 256: [0,4096) cast, [4096,8192) trans, [8192,8448) rope.
__global__ void prep_kernel(const float* __restrict__ x,
                            const float* __restrict__ w0, const float* __restrict__ w1,
                            const float* __restrict__ w2, const float* __restrict__ w3,
                            unsigned short* __restrict__ xc,
                            unsigned short* __restrict__ wt,
                            float2* __restrict__ rope) {
  const int bid = blockIdx.x;
  if (bid < 4096) {                       // cast: 4 f32 -> bf16 per thread
    int i = (bid * 256 + threadIdx.x) * 4;
    float4 v = *(const float4*)(x + i);
    ushort4 o;
    o.x = f2b(v.x); o.y = f2b(v.y); o.z = f2b(v.z); o.w = f2b(v.w);
    *(ushort4*)(xc + i) = o;
  } else if (bid < 8192) {                // weight transpose: Wt[n][k] = W[k][n]
    __shared__ float tile[32][33];
    const int rem = bid - 4096;
    const int z = rem >> 10;
    const int bx = (rem & 1023) & 31;
    const int by = (rem & 1023) >> 5;
    const float* W = (z == 0) ? w0 : (z == 1) ? w1 : (z == 2) ? w2 : w3;
    unsigned short* Wt = wt + (size_t)z * DM * DM;
    const int tx = threadIdx.x & 31;
    const int ty = threadIdx.x >> 5;
    const int k0 = bx * 32;
    const int c0 = by * 32;
#pragma unroll
    for (int i = 0; i < 4; ++i)
      tile[ty + i * 8][tx] = W[(size_t)(k0 + ty + i * 8) * DM + c0 + tx];
    __syncthreads();
#pragma unroll
    for (int i = 0; i < 4; ++i)
      Wt[(size_t)(c0 + ty + i * 8) * DM + k0 + tx] = f2b(tile[tx][ty + i * 8]);
  } else {                                // rope: tab[s][d2] = (cos, sin)
    int i = (bid - 8192) * 256 + threadIdx.x;  // 65536 = 2048*32
    int s = i >> 5, d2 = i & 31;
    float th = expf(-(float)d2 * (9.210340371976184f / 32.0f));
    float sn, cs;
    sincosf((float)s * th, &sn, &cs);
    rope[i] = make_float2(cs, sn);
  }
}

// ---------------- fused QKV GEMM: 128x64 tile, 1536 blocks = 6/CU ----------------
// A[4096][1024] bf16 x Wt_qkv[3072][1024]^T. grid (32,48). mat = by>>4:
// 0=Q (RoPE + 0.125*log2e), 1=K (RoPE) -> [bh][s][d]; 2=V -> VT[bh][d][s].
__global__ __launch_bounds__(256, 4) void gemm_qkv(
    const unsigned short* __restrict__ A, const unsigned short* __restrict__ Wt,
    const float* __restrict__ bq, const float* __restrict__ bk,
    const float* __restrict__ bv, const float2* __restrict__ rope,
    unsigned short* __restrict__ QKV, unsigned short* __restrict__ VT) {
  __shared__ __attribute__((aligned(16))) unsigned short As[64 * 136];  // also V^T staging
  __shared__ __attribute__((aligned(16))) unsigned short Bs[64 * 64];
  const int r0 = blockIdx.x * 128;
  const int c0 = blockIdx.y * 64;
  const int t = threadIdx.x;
  const int lane = t & 63;
  const int wv = t >> 6;
  const int wr = (wv >> 1) * 64;   // 2 wave-rows x 64
  const int wc = (wv & 1) * 32;    // 2 wave-cols x 32
  const int lr = lane & 15;
  const int lg = lane >> 4;

  // staging: A rows [wv*32,+32) via 4 gloads; B rows [wv*16,+16) via 2 gloads
  const int chunk = lane >> 3;
  const int sseg = ((lane & 7) ^ chunk) * 8;
  const unsigned short* Ag = A + (size_t)(r0 + wv * 32 + chunk) * DM + sseg;
  const unsigned short* Bg = Wt + (size_t)(c0 + wv * 16 + chunk) * DM + sseg;
  unsigned short* lA = &As[wv * 32 * 64];
  unsigned short* lB = &Bs[wv * 16 * 64];

  floatx4 acc[4][2] = {};
  const int fswz = (lr & 7) << 4;

  for (int k0 = 0; k0 < DM; k0 += 64) {
#pragma unroll
    for (int j = 0; j < 4; ++j)
      gload_lds16(Ag + k0 + j * 8 * DM, lA + j * 8 * 64);
#pragma unroll
    for (int j = 0; j < 2; ++j)
      gload_lds16(Bg + k0 + j * 8 * DM, lB + j * 8 * 64);
    __syncthreads();
#pragma unroll
    for (int kk = 0; kk < 2; ++kk) {
      short8 af[4], bf[2];
#pragma unroll
      for (int m = 0; m < 4; ++m)
        af[m] = *(const short8*)((char*)As + (wr + m * 16 + lr) * 128 +
                                 ((kk * 64 + lg * 16) ^ fswz));
#pragma unroll
      for (int n = 0; n < 2; ++n)
        bf[n] = *(const short8*)((char*)Bs + (wc + n * 16 + lr) * 128 +
                                 ((kk * 64 + lg * 16) ^ fswz));
#pragma unroll
      for (int m = 0; m < 4; ++m)
#pragma unroll
        for (int n = 0; n < 2; ++n)
          acc[m][n] = __builtin_amdgcn_mfma_f32_16x16x32_bf16(af[m], bf[n], acc[m][n], 0, 0, 0);
    }
    __syncthreads();
  }

  const int mat = blockIdx.y >> 4;
  const float* bias = (mat == 0) ? bq : (mat == 1) ? bk : bv;
  const int rbase = r0 + wr + lg * 4;
  const int cbase = c0 + wc + lr;

  if (mat == 2) {
    // V^T path: stage [d_local 0..63][s_local 0..127] in LDS (pad 136), then
    // coalesced 16B writes: 64 rows x 16 segs = 1024 int4 by 256 thr x 4.
    unsigned short* Ls = As;  // free after final loop barrier
#pragma unroll
    for (int n = 0; n < 2; ++n) {
      const int dl = wc + n * 16 + lr;          // 0..63
      const float bvv = bias[(c0 & (DM - 1)) + dl];
#pragma unroll
      for (int m = 0; m < 4; ++m)
#pragma unroll
        for (int i = 0; i < 4; ++i)
          Ls[dl * 136 + (wr + m * 16 + lg * 4 + i)] = f2b(acc[m][n][i] + bvv);
    }
    __syncthreads();
    const int b2 = r0 >> 11;
    const int h2 = (c0 & (DM - 1)) >> 6;
    const int s0 = r0 & (S_ - 1);
    unsigned short* VTb = VT + ((size_t)((b2 << 4) | h2) * 64) * S_ + s0;
#pragma unroll
    for (int j = 0; j < 4; ++j) {
      const int idx = t + j * 256;   // 0..1023
      const int d = idx >> 4;        // 0..63
      const int sg = idx & 15;       // 16B seg of the 128-col row
      *(int4*)(VTb + (size_t)d * S_ + sg * 8) = *(const int4*)(Ls + d * 136 + sg * 8);
    }
  } else {
#pragma unroll
    for (int n = 0; n < 2; ++n) {
      const int c = cbase + n * 16;
      const int cc = c & (DM - 1);
      const float bvv = bias[cc];
      const int d = c & 63;
      const int h = cc >> 6;
#pragma unroll
      for (int m = 0; m < 4; ++m) {
#pragma unroll
        for (int i = 0; i < 4; ++i) {
          const int r = rbase + m * 16 + i;
          const int s = r & (S_ - 1);
          const int b = r >> 11;
          float v = acc[m][n][i] + bvv;
          float pv = __shfl_xor(v, 1);
          float2 cssn = rope[s * 32 + (d >> 1)];
          v = (d & 1) ? fmaf(v, cssn.x, pv * cssn.y) : fmaf(v, cssn.x, -pv * cssn.y);
          if (mat == 0) v *= 0.18033688011112042f;  // 0.125 * log2(e)
          QKV[((size_t)((mat << 5) | (b << 4) | h) * S_ + s) * HD + d] = f2b(v);
        }
      }
    }
  }
}

// ---------------- out projection GEMM: 64x64 tile, 1024 blocks = 4/CU ----------------
__global__ __launch_bounds__(256, 4) void gemm_out(
    const unsigned short* __restrict__ A, const unsigned short* __restrict__ Wt,
    const float* __restrict__ bias, float* __restrict__ out) {
  __shared__ __attribute__((aligned(16))) unsigned short As[64 * 64];
  __shared__ __attribute__((aligned(16))) unsigned short Bs[64 * 64];
  const int r0 = blockIdx.x * 64;
  const int c0 = blockIdx.y * 64;
  const int t = threadIdx.x;
  const int lane = t & 63;
  const int wv = t >> 6;
  const int wr = (wv >> 1) * 32;
  const int wc = (wv & 1) * 32;
  const int lr = lane & 15;
  const int lg = lane >> 4;

  const int chunk = lane >> 3;
  const int sseg = ((lane & 7) ^ chunk) * 8;
  const unsigned short* Ag = A + (size_t)(r0 + wv * 8 + chunk) * DM + sseg;
  const unsigned short* Bg = Wt + (size_t)(c0 + wv * 8 + chunk) * DM + sseg;
  unsigned short* lA = &As[wv * 8 * 64];
  unsigned short* lB = &Bs[wv * 8 * 64];

  floatx4 acc[2][2] = {};
  const int fswz = (lr & 7) << 4;

  for (int k0 = 0; k0 < DM; k0 += 64) {
#pragma unroll
    for (int j = 0; j < 2; ++j) {
      gload_lds16(Ag + k0 + j * 32 * DM, lA + j * 32 * 64);
      gload_lds16(Bg + k0 + j * 32 * DM, lB + j * 32 * 64);
    }
    __syncthreads();
#pragma unroll
    for (int kk = 0; kk < 2; ++kk) {
      short8 af[2], bf[2];
#pragma unroll
      for (int m = 0; m < 2; ++m)
        af[m] = *(const short8*)((char*)As + (wr + m * 16 + lr) * 128 +
                                 ((kk * 64 + lg * 16) ^ fswz));
#pragma unroll
      for (int n = 0; n < 2; ++n)
        bf[n] = *(const short8*)((char*)Bs + (wc + n * 16 + lr) * 128 +
                                 ((kk * 64 + lg * 16) ^ fswz));
#pragma unroll
      for (int m = 0; m < 2; ++m)
#pragma unroll
        for (int n = 0; n < 2; ++n)
          acc[m][n] = __builtin_amdgcn_mfma_f32_16x16x32_bf16(af[m], bf[n], acc[m][n], 0, 0, 0);
    }
    __syncthreads();
  }

  const int rbase = r0 + wr + lg * 4;
  const int cbase = c0 + wc + lr;
#pragma unroll
  for (int n = 0; n < 2; ++n) {
    const int c = cbase + n * 16;
    const float bvv = bias[c];
#pragma unroll
    for (int m = 0; m < 2; ++m) {
#pragma unroll
      for (int i = 0; i < 4; ++i) {
        const int r = rbase + m * 16 + i;
        out[(size_t)r * DM + c] = acc[m][n][i] + bvv;
      }
    }
  }
}

// ---------------- MFMA flash attention v12b: pure-DMA K+V staging ----------------
// grid (bh=32, y=32), 256 thr = 4 waves, qt = 31-y (LPT). Prologue: 4 DMAs +
// vmcnt(0) + barrier (tile-0 cross-wave visibility). Per tile: lgkmcnt+barrier,
// issue 4 DMAs for t+1, vmcnt(4) (own tile-t DMAs done, t+1 in flight; cross-
// wave safe by >=1 tile-compute margin, same class as 12-round-verified R8).
#define ATTN_STEP(TT, BUF, KLA, KLB, VLA, VLB)                                 \
  do {                                                                         \
    asm volatile("s_waitcnt lgkmcnt(0)" ::: "memory");                         \
    __builtin_amdgcn_s_barrier();                                              \
    if ((TT) < qt) { /* DMA tile TT+1 -> other buffer */                       \
      gload_lds16(Kpref, KLA);                                                 \
      gload_lds16(Kpref + 2048, KLB);                                          \
      gload_lds16(VTpref, VLA);                                                \
      gload_lds16(VTpref + 32 * S_, VLB);                                      \
      Kpref += 4096;                                                           \
      VTpref += 64;                                                            \
      asm volatile("s_waitcnt vmcnt(4)" ::: "memory");                         \
    } else {                                                                   \
      asm volatile("s_waitcnt vmcnt(0)" ::: "memory");                         \
    }                                                                          \
    __builtin_amdgcn_sched_barrier(0);                                         \
    /* S^T = K Q^T : s[n][i] = S[key=n*16+lg*4+i][q=lr] */                     \
    floatx4 s[4] = {};                                                         \
    __builtin_amdgcn_s_setprio(1);                                             \
    _Pragma("unroll") for (int kk = 0; kk < 2; ++kk) {                         \
      _Pragma("unroll") for (int n = 0; n < 4; ++n) {                          \
        int r = n * 16 + lr;                                                   \
        short8 kf = *(const short8*)((char*)Ks[BUF] + r * 128 +                \
                                     ((kk * 64 + lg * 16) ^ ((r & 7) << 4)));  \
        s[n] = __builtin_amdgcn_mfma_f32_16x16x32_bf16(kf, qf[kk], s[n], 0, 0, 0); \
      }                                                                        \
    }                                                                          \
    __builtin_amdgcn_s_setprio(0);                                             \
    if ((TT) == qt) {                                                          \
      _Pragma("unroll") for (int n = 0; n < 4; ++n)                            \
        _Pragma("unroll") for (int i = 0; i < 4; ++i)                          \
          if (n * 16 + lg * 4 + i > qin) s[n][i] = -1e30f;                     \
    }                                                                          \
    /* in-lane 16-max only (max3-friendly triples) */                          \
    float ta = fmaxf(fmaxf(s[0][0], s[0][1]), s[0][2]);                        \
    float tb = fmaxf(fmaxf(s[0][3], s[1][0]), s[1][1]);                        \
    float tc = fmaxf(fmaxf(s[1][2], s[1][3]), s[2][0]);                        \
    float td = fmaxf(fmaxf(s[2][1], s[2][2]), s[2][3]);                        \
    float te = fmaxf(fmaxf(s[3][0], s[3][1]), s[3][2]);                        \
    float tm = fmaxf(fmaxf(ta, tb), tc);                                       \
    tm = fmaxf(fmaxf(tm, td), te);                                             \
    tm = fmaxf(tm, s[3][3]);                                                   \
    /* lazy max: cross-lane shuffles + rescale only when triggered */          \
    if (__any(tm > m + 8.f)) {                                                 \
      tm = fmaxf(tm, __shfl_xor(tm, 16));                                      \
      tm = fmaxf(tm, __shfl_xor(tm, 32));                                      \
      const float mn = fmaxf(m, tm);                                           \
      const float al = exp2f(m - mn);                                          \
      m = mn;                                                                  \
      lsum *= al;                                                              \
      _Pragma("unroll") for (int dd = 0; dd < 4; ++dd) o[dd] *= al;            \
    }                                                                          \
    float ps = 0.f;                                                            \
    _Pragma("unroll") for (int n = 0; n < 4; ++n) {                            \
      _Pragma("unroll") for (int i = 0; i < 4; ++i) {                          \
        float p = exp2f(s[n][i] - m);                                          \
        s[n][i] = p;                                                           \
        ps += p;                                                               \
      }                                                                        \
    }                                                                          \
    lsum += ps;                                                                \
    /* P^T rows into Ps[w] via cvt_pk (1 VALU per pair) */                     \
    _Pragma("unroll") for (int n = 0; n < 4; ++n) {                            \
      _Pragma("unroll") for (int hh = 0; hh < 2; ++hh) {                       \
        unsigned pk = cvt_pk_bf16(s[n][2 * hh], s[n][2 * hh + 1]);             \
        *(unsigned*)(Pw + lr * 128 +                                           \
                     (((n * 16 + lg * 4 + 2 * hh) * 2) ^ pswz)) = pk;          \
      }                                                                        \
    }                                                                          \
    short8 pb[2];                                                              \
    _Pragma("unroll") for (int kk = 0; kk < 2; ++kk)                           \
      pb[kk] = *(const short8*)(Pw + lr * 128 + ((kk * 64 + lg * 16) ^ pswz)); \
    __builtin_amdgcn_s_setprio(1);                                             \
    _Pragma("unroll") for (int kk = 0; kk < 2; ++kk)                           \
      _Pragma("unroll") for (int dd = 0; dd < 4; ++dd) {                       \
        int d = dd * 16 + lr;                                                  \
        short8 vbf = *(const short8*)((char*)Vs[BUF] + d * 128 +               \
                                      ((kk * 64 + lg * 16) ^ ((d & 7) << 4))); \
        o[dd] = __builtin_amdgcn_mfma_f32_16x16x32_bf16(vbf, pb[kk], o[dd], 0, 0, 0); \
      }                                                                        \
    __builtin_amdgcn_s_setprio(0);                                             \
  } while (0)

__global__ __launch_bounds__(256, 4) void attn_kernel(
    const unsigned short* __restrict__ Q, const unsigned short* __restrict__ K,
    const unsigned short* __restrict__ VT, unsigned short* __restrict__ AttnC) {
  __shared__ __attribute__((aligned(16))) unsigned short Ks[2][64 * 64];
  __shared__ __attribute__((aligned(16))) unsigned short Vs[2][64 * 64];
  __shared__ __attribute__((aligned(16))) unsigned short Ps[4][16 * 64];

  const int bh = blockIdx.x;
  const int qt = 31 - (int)blockIdx.y;  // LPT: big blocks first
  const int tid = threadIdx.x;
  const int w = tid >> 6;
  const int l = tid & 63;
  const int lg = l >> 4;
  const int lr = l & 15;
  const size_t base = (size_t)bh * S_ * HD;
  const int qin = w * 16 + lr;

  // Q as B-frag: B[k][q=lr] = Q[q][k], k = kk*32 + lg*8 + j
  short8 qf[2];
  {
    const unsigned short* Qrow =
        Q + base + (size_t)(qt * 64 + w * 16 + lr) * HD + lg * 8;
    qf[0] = *(const short8*)(Qrow);
    qf[1] = *(const short8*)(Qrow + 32);
  }

  floatx4 o[4] = {};
  float m = -1e30f, lsum = 0.f;

  // K: rows (keys) krow; V^T: rows (dims) krow. Both pre-swizzled sources ->
  // linear LDS (rule #21 both-sides pattern), read side XOR-swizzled.
  const int krow = tid >> 3;
  const int kseg = tid & 7;
  const unsigned short* Kpref = K + base + krow * 64 + ((kseg ^ (krow & 7)) * 8);
  const unsigned short* VTpref =
      VT + ((size_t)bh * 64 + krow) * S_ + ((kseg ^ (krow & 7)) * 8);
  unsigned short* const kld0a = &Ks[0][w * 512];
  unsigned short* const kld0b = &Ks[0][2048 + w * 512];
  unsigned short* const kld1a = &Ks[1][w * 512];
  unsigned short* const kld1b = &Ks[1][2048 + w * 512];
  unsigned short* const vld0a = &Vs[0][w * 512];
  unsigned short* const vld0b = &Vs[0][2048 + w * 512];
  unsigned short* const vld1a = &Vs[1][w * 512];
  unsigned short* const vld1b = &Vs[1][2048 + w * 512];

  // prologue: tile 0 DMAs into buf0, then DRAIN + BARRIER so every wave sees
  // every other wave's tile-0 rows (fixes the R21 cross-wave visibility race).
  gload_lds16(Kpref, kld0a);
  gload_lds16(Kpref + 2048, kld0b);
  gload_lds16(VTpref, vld0a);
  gload_lds16(VTpref + 32 * S_, vld0b);
  Kpref += 4096;
  VTpref += 64;
  asm volatile("s_waitcnt vmcnt(0)" ::: "memory");
  __builtin_amdgcn_s_barrier();

  char* const Pw = (char*)Ps[w];
  const int pswz = (lr & 7) << 4;

  int t = 0;
#pragma unroll 1
  for (; t + 1 <= qt; t += 2) {
    ATTN_STEP(t, 0, kld1a, kld1b, vld1a, vld1b);
    ATTN_STEP(t + 1, 1, kld0a, kld0b, vld0a, vld0b);
  }
  if (t <= qt) ATTN_STEP(t, 0, kld1a, kld1b, vld1a, vld1b);

  // reduce lsum across the 4 lg-partials, write O[q=lr][d=dd*16+lg*4+i]
  lsum += __shfl_xor(lsum, 16);
  lsum += __shfl_xor(lsum, 32);
  const float inv = 1.f / lsum;
  unsigned short* orow =
      AttnC + (size_t)((bh >> 4) * S_ + qt * 64 + w * 16 + lr) * DM + (bh & 15) * HD;
#pragma unroll
  for (int dd = 0; dd < 4; ++dd) {
    unsigned w0 = cvt_pk_bf16(o[dd][0] * inv, o[dd][1] * inv);
    unsigned w1 = cvt_pk_bf16(o[dd][2] * inv, o[dd][3] * inv);
    *(uint2*)(orow + dd * 16 + lg * 4) = make_uint2(w0, w1);
  }
}

extern "C" void kernel_launch(void* const* d_in, const int* in_sizes, int n_in,
                              void* d_out, int out_size, void* d_ws, size_t ws_size,
                              hipStream_t stream) {
  const float* x = (const float*)d_in[0];
  const float* wq = (const float*)d_in[2];
  const float* bq = (const float*)d_in[3];
  const float* wk = (const float*)d_in[4];
  const float* bk = (const float*)d_in[5];
  const float* wv = (const float*)d_in[6];
  const float* bv = (const float*)d_in[7];
  const float* wo = (const float*)d_in[8];
  const float* bo = (const float*)d_in[9];

  char* ws = (char*)d_ws;
  const size_t MB = 1024ull * 1024ull;
  unsigned short* Xc = (unsigned short*)(ws);             // 8 MB
  unsigned short* Wt = (unsigned short*)(ws + 8 * MB);    // 4 x 2 MB
  unsigned short* QKVb = (unsigned short*)(ws + 16 * MB); // Q 8MB | K 8MB
  unsigned short* VTb = (unsigned short*)(ws + 32 * MB);  // VT 8MB [bh][d][s]
  unsigned short* Ac = (unsigned short*)(ws + 40 * MB);   // 8 MB
  float2* rope = (float2*)(ws + 48 * MB);                 // 0.5 MB

  prep_kernel<<<8448, 256, 0, stream>>>(x, wq, wk, wv, wo, Xc, Wt, rope);
  gemm_qkv<<<dim3(32, 48), 256, 0, stream>>>(Xc, Wt, bq, bk, bv, rope, QKVb, VTb);
  attn_kernel<<<dim3(32, 32), 256, 0, stream>>>(
      QKVb, QKVb + 32ull * S_ * HD, VTb, Ac);
  gemm_out<<<dim3(64, 16), 256, 0, stream>>>(Ac, Wt + 3ull * DM * DM, bo, (float*)d_out);
}